// Round 1
// baseline (86.043 us; speedup 1.0000x reference)
//
#include <hip/hip_runtime.h>

#ifndef NRAYS_DEFAULT
#define NRAYS_DEFAULT 4194304
#endif

__global__ __launch_bounds__(256) void refract4_kernel(
    const float4* __restrict__ P4,
    const float4* __restrict__ V4,
    const float4* __restrict__ B4,
    const float4* __restrict__ W4,
    float4* __restrict__ outP,
    float4* __restrict__ outV,
    float4* __restrict__ outB,
    float4* __restrict__ outW,
    float4* __restrict__ outBV,
    float4* __restrict__ outVR,
    int nGroups)
{
    const int t = blockIdx.x * blockDim.x + threadIdx.x;
    if (t >= nGroups) return;

    // Load 4 rays' worth of data: 12 floats of P, V, base; 4 wavelengths.
    float p[12], v[12], rb[12], w[4];
    {
        float4 a;
        a = P4[3*t+0]; p[0]=a.x; p[1]=a.y; p[2]=a.z;  p[3]=a.w;
        a = P4[3*t+1]; p[4]=a.x; p[5]=a.y; p[6]=a.z;  p[7]=a.w;
        a = P4[3*t+2]; p[8]=a.x; p[9]=a.y; p[10]=a.z; p[11]=a.w;
        a = V4[3*t+0]; v[0]=a.x; v[1]=a.y; v[2]=a.z;  v[3]=a.w;
        a = V4[3*t+1]; v[4]=a.x; v[5]=a.y; v[6]=a.z;  v[7]=a.w;
        a = V4[3*t+2]; v[8]=a.x; v[9]=a.y; v[10]=a.z; v[11]=a.w;
        a = B4[3*t+0]; rb[0]=a.x; rb[1]=a.y; rb[2]=a.z;  rb[3]=a.w;
        a = B4[3*t+1]; rb[4]=a.x; rb[5]=a.y; rb[6]=a.z;  rb[7]=a.w;
        a = B4[3*t+2]; rb[8]=a.x; rb[9]=a.y; rb[10]=a.z; rb[11]=a.w;
        a = W4[t];     w[0]=a.x; w[1]=a.y; w[2]=a.z;  w[3]=a.w;
    }

    float oP[12], oV[12], oB[12], oW[4], oBV[4], oVR[4];

    #pragma unroll
    for (int j = 0; j < 4; ++j) {
        const float px = p[3*j+0], py = p[3*j+1], pz = p[3*j+2];
        const float vx = v[3*j+0], vy = v[3*j+1], vz = v[3*j+2];

        // oc = P - center, center = (0,0,60)
        const float ocx = px, ocy = py, ocz = pz - 60.0f;
        const float b = ocx*vx + ocy*vy + ocz*vz;
        const float c = ocx*ocx + ocy*ocy + ocz*ocz - 2500.0f;  // R^2 = 2500
        const float disc = b*b - c;
        const bool valid_collision = (disc >= 0.0f);
        const float sqrt_disc = valid_collision ? sqrtf(disc) : 0.0f;
        const float tt = -b - sqrt_disc;

        const float Xx = px + tt*vx;
        const float Xy = py + tt*vy;
        const float Xz = pz + tt*vz;

        const float invR = 1.0f / 50.0f;
        const float nx = Xx * invR;
        const float ny = Xy * invR;
        const float nz = (Xz - 60.0f) * invR;

        const float dotVN = vx*nx + vy*ny + vz*nz;
        const float s = (dotVN > 0.0f) ? -1.0f : 1.0f;
        const float nfx = s*nx, nfy = s*ny, nfz = s*nz;

        const float cos_i = -(vx*nfx + vy*nfy + vz*nfz);

        const float lam = w[j];
        const float inv_l2 = 1.0f / (lam * lam);
        // n1 = 1.0 + 0.0*inv_l2 = 1.0
        const float n2 = 1.5046f + 0.0042f * inv_l2;
        const float eta = 1.0f / n2;

        const float sin2_t = eta*eta*(1.0f - cos_i*cos_i);
        const bool tir = (sin2_t > 1.0f);
        const float cos_t = tir ? 0.0f : sqrtf(1.0f - sin2_t);

        const float k = eta*cos_i - cos_t;
        // refracted = eta*V + k*nf ; reflected = V + 2*cos_i*nf
        float ox, oy, oz;
        if (tir) {
            ox = vx + 2.0f*cos_i*nfx;
            oy = vy + 2.0f*cos_i*nfy;
            oz = vz + 2.0f*cos_i*nfz;
        } else {
            ox = eta*vx + k*nfx;
            oy = eta*vy + k*nfy;
            oz = eta*vz + k*nfz;
        }

        const bool both = valid_collision && !tir;
        const float m = both ? 1.0f : 0.0f;

        oP[3*j+0] = both ? Xx : 0.0f;
        oP[3*j+1] = both ? Xy : 0.0f;
        oP[3*j+2] = both ? Xz : 0.0f;
        oV[3*j+0] = both ? ox : 0.0f;
        oV[3*j+1] = both ? oy : 0.0f;
        oV[3*j+2] = both ? oz : 0.0f;
        oB[3*j+0] = both ? rb[3*j+0] : 0.0f;
        oB[3*j+1] = both ? rb[3*j+1] : 0.0f;
        oB[3*j+2] = both ? rb[3*j+2] : 0.0f;
        oW[j]  = both ? lam : 0.0f;
        oBV[j] = m;
        oVR[j] = tir ? 0.0f : 1.0f;
    }

    outP[3*t+0] = make_float4(oP[0], oP[1], oP[2],  oP[3]);
    outP[3*t+1] = make_float4(oP[4], oP[5], oP[6],  oP[7]);
    outP[3*t+2] = make_float4(oP[8], oP[9], oP[10], oP[11]);
    outV[3*t+0] = make_float4(oV[0], oV[1], oV[2],  oV[3]);
    outV[3*t+1] = make_float4(oV[4], oV[5], oV[6],  oV[7]);
    outV[3*t+2] = make_float4(oV[8], oV[9], oV[10], oV[11]);
    outB[3*t+0] = make_float4(oB[0], oB[1], oB[2],  oB[3]);
    outB[3*t+1] = make_float4(oB[4], oB[5], oB[6],  oB[7]);
    outB[3*t+2] = make_float4(oB[8], oB[9], oB[10], oB[11]);
    outW[t]  = make_float4(oW[0],  oW[1],  oW[2],  oW[3]);
    outBV[t] = make_float4(oBV[0], oBV[1], oBV[2], oBV[3]);
    outVR[t] = make_float4(oVR[0], oVR[1], oVR[2], oVR[3]);
}

extern "C" void kernel_launch(void* const* d_in, const int* in_sizes, int n_in,
                              void* d_out, int out_size, void* d_ws, size_t ws_size,
                              hipStream_t stream) {
    const int N = in_sizes[3];           // rays_wavelength has N elements
    const int nGroups = N / 4;

    const float4* P4 = (const float4*)d_in[0];
    const float4* V4 = (const float4*)d_in[1];
    const float4* B4 = (const float4*)d_in[2];
    const float4* W4 = (const float4*)d_in[3];

    float* out = (float*)d_out;
    float4* outP  = (float4*)(out + (size_t)0 * N);
    float4* outV  = (float4*)(out + (size_t)3 * N);
    float4* outB  = (float4*)(out + (size_t)6 * N);
    float4* outW  = (float4*)(out + (size_t)9 * N);
    float4* outBV = (float4*)(out + (size_t)10 * N);
    float4* outVR = (float4*)(out + (size_t)11 * N);

    const int block = 256;
    const int grid = (nGroups + block - 1) / block;
    refract4_kernel<<<grid, block, 0, stream>>>(P4, V4, B4, W4,
                                                outP, outV, outB, outW, outBV, outVR,
                                                nGroups);
}

// Round 2
// 75.497 us; speedup vs baseline: 1.1397x; 1.1397x over previous
//
#include <hip/hip_runtime.h>

#define BLOCK 256
#define RPB   1024   // rays per block

__global__ __launch_bounds__(BLOCK) void refract_lds_kernel(
    const float4* __restrict__ Pg,
    const float4* __restrict__ Vg,
    const float4* __restrict__ Bg,
    const float*  __restrict__ Wg,
    float4* __restrict__ outP,
    float4* __restrict__ outV,
    float4* __restrict__ outB,
    float4* __restrict__ outW,
    float4* __restrict__ outBV,
    float4* __restrict__ outVR)
{
    __shared__ float sP[RPB*3];   // 12 KB — in: P, out: masked X
    __shared__ float sV[RPB*3];   // 12 KB — in: V, out: masked out_dir
    __shared__ float sW[RPB];     //  4 KB — masked wavelength
    __shared__ float sBV[RPB];    //  4 KB — both_valid mask (1/0)
    __shared__ float sVR[RPB];    //  4 KB — valid_refraction (1/0)

    const int tid = threadIdx.x;
    const long long blk    = blockIdx.x;
    const long long v4base = blk * (RPB*3/4);  // float4 index into vec3 streams
    const long long w4base = blk * (RPB/4);    // float4 index into scalar streams
    const long long rayBase = blk * RPB;

    float4* sP4 = (float4*)sP;
    float4* sV4 = (float4*)sV;

    // Phase 1: coalesced staging of P,V; prefetch lambda + rays_base into regs.
    float lam[4];
    float4 bb[3];
    #pragma unroll
    for (int k = 0; k < 3; ++k) {
        sP4[k*BLOCK + tid] = Pg[v4base + k*BLOCK + tid];
        sV4[k*BLOCK + tid] = Vg[v4base + k*BLOCK + tid];
        bb[k]              = Bg[v4base + k*BLOCK + tid];
    }
    #pragma unroll
    for (int j = 0; j < 4; ++j)
        lam[j] = Wg[rayBase + tid + j*BLOCK];
    __syncthreads();

    // Phase 2: each thread computes 4 rays (stride-256 assignment; LDS word
    // addresses 3r with odd stride -> <=2-way bank aliasing, free).
    #pragma unroll
    for (int j = 0; j < 4; ++j) {
        const int r = tid + j*BLOCK;
        const float px = sP[3*r+0], py = sP[3*r+1], pz = sP[3*r+2];
        const float vx = sV[3*r+0], vy = sV[3*r+1], vz = sV[3*r+2];

        // oc = P - center, center=(0,0,60), R^2 = 2500
        const float ocx = px, ocy = py, ocz = pz - 60.0f;
        const float b = ocx*vx + ocy*vy + ocz*vz;
        const float c = ocx*ocx + ocy*ocy + ocz*ocz - 2500.0f;
        const float disc = b*b - c;
        const bool valid_collision = (disc >= 0.0f);
        const float sqrt_disc = valid_collision ? sqrtf(disc) : 0.0f;
        const float tt = -b - sqrt_disc;

        const float Xx = px + tt*vx;
        const float Xy = py + tt*vy;
        const float Xz = pz + tt*vz;

        const float invR = 1.0f / 50.0f;
        const float nx = Xx * invR;
        const float ny = Xy * invR;
        const float nz = (Xz - 60.0f) * invR;

        const float dotVN = vx*nx + vy*ny + vz*nz;
        const float s = (dotVN > 0.0f) ? -1.0f : 1.0f;
        const float nfx = s*nx, nfy = s*ny, nfz = s*nz;

        const float cos_i = -(vx*nfx + vy*nfy + vz*nfz);

        const float l = lam[j];
        const float inv_l2 = 1.0f / (l * l);
        const float n2 = 1.5046f + 0.0042f * inv_l2;   // n1 = 1.0
        const float eta = 1.0f / n2;

        const float sin2_t = eta*eta*(1.0f - cos_i*cos_i);
        const bool tir = (sin2_t > 1.0f);
        const float cos_t = tir ? 0.0f : sqrtf(1.0f - sin2_t);

        const float k = eta*cos_i - cos_t;
        float ox, oy, oz;
        if (tir) {
            ox = vx + 2.0f*cos_i*nfx;
            oy = vy + 2.0f*cos_i*nfy;
            oz = vz + 2.0f*cos_i*nfz;
        } else {
            ox = eta*vx + k*nfx;
            oy = eta*vy + k*nfy;
            oz = eta*vz + k*nfz;
        }

        const bool both = valid_collision && !tir;
        const float m = both ? 1.0f : 0.0f;

        sP[3*r+0] = both ? Xx : 0.0f;
        sP[3*r+1] = both ? Xy : 0.0f;
        sP[3*r+2] = both ? Xz : 0.0f;
        sV[3*r+0] = both ? ox : 0.0f;
        sV[3*r+1] = both ? oy : 0.0f;
        sV[3*r+2] = both ? oz : 0.0f;
        sW[r]  = both ? l : 0.0f;
        sBV[r] = m;
        sVR[r] = tir ? 0.0f : 1.0f;
    }
    __syncthreads();

    // Phase 3: fully coalesced float4 stores. rays_base is a masked
    // passthrough: use the prefetched registers, mask per component.
    #pragma unroll
    for (int k = 0; k < 3; ++k) {
        outP[v4base + k*BLOCK + tid] = sP4[k*BLOCK + tid];
        outV[v4base + k*BLOCK + tid] = sV4[k*BLOCK + tid];
        const int fi = (k*BLOCK + tid) * 4;   // local float index 0..3071
        float4 ob = bb[k];
        ob.x *= sBV[(fi+0)/3];
        ob.y *= sBV[(fi+1)/3];
        ob.z *= sBV[(fi+2)/3];
        ob.w *= sBV[(fi+3)/3];
        outB[v4base + k*BLOCK + tid] = ob;
    }
    outW [w4base + tid] = ((float4*)sW )[tid];
    outBV[w4base + tid] = ((float4*)sBV)[tid];
    outVR[w4base + tid] = ((float4*)sVR)[tid];
}

extern "C" void kernel_launch(void* const* d_in, const int* in_sizes, int n_in,
                              void* d_out, int out_size, void* d_ws, size_t ws_size,
                              hipStream_t stream) {
    const int N = in_sizes[3];           // rays_wavelength element count
    const int nBlocks = N / RPB;

    const float4* Pg = (const float4*)d_in[0];
    const float4* Vg = (const float4*)d_in[1];
    const float4* Bg = (const float4*)d_in[2];
    const float*  Wg = (const float*)d_in[3];

    float* out = (float*)d_out;
    float4* outP  = (float4*)(out + (size_t)0  * N);
    float4* outV  = (float4*)(out + (size_t)3  * N);
    float4* outB  = (float4*)(out + (size_t)6  * N);
    float4* outW  = (float4*)(out + (size_t)9  * N);
    float4* outBV = (float4*)(out + (size_t)10 * N);
    float4* outVR = (float4*)(out + (size_t)11 * N);

    refract_lds_kernel<<<nBlocks, BLOCK, 0, stream>>>(Pg, Vg, Bg, Wg,
                                                      outP, outV, outB, outW,
                                                      outBV, outVR);
}

// Round 3
// 71.120 us; speedup vs baseline: 1.2098x; 1.0615x over previous
//
#include <hip/hip_runtime.h>

#define BLOCK 512
#define RPB   1024          // rays per block
#define V4PB  768           // float4s per vec3 stream per block (RPB*3/4)
#define S4PB  256           // float4s per scalar stream per block (RPB/4)

typedef float f4v __attribute__((ext_vector_type(4)));

static __device__ __forceinline__ f4v ntload4(const f4v* p) {
    return __builtin_nontemporal_load(p);
}
static __device__ __forceinline__ void ntstore4(f4v v, f4v* p) {
    __builtin_nontemporal_store(v, p);
}

__global__ __launch_bounds__(BLOCK, 8) void refract_lds_kernel(
    const f4v* __restrict__ Pg,
    const f4v* __restrict__ Vg,
    const f4v* __restrict__ Bg,
    const f4v* __restrict__ Wg4,
    f4v* __restrict__ outP,
    f4v* __restrict__ outV,
    f4v* __restrict__ outB,
    f4v* __restrict__ outW,
    f4v* __restrict__ outBV,
    f4v* __restrict__ outVR)
{
    __shared__ float sP[RPB*3];   // 12 KB — in: P, out: masked X
    __shared__ float sV[RPB*3];   // 12 KB — in: V, out: masked out_dir
    __shared__ float sW[RPB];     //  4 KB — in: lambda, out: masked lambda
    __shared__ float sBV[RPB];    //  4 KB — both_valid mask
    __shared__ float sVR[RPB];    //  4 KB — valid_refraction mask

    const int tid = threadIdx.x;
    const int blk = blockIdx.x;
    const int v4base = blk * V4PB;
    const int w4base = blk * S4PB;

    f4v* sP4 = (f4v*)sP;
    f4v* sV4 = (f4v*)sV;
    f4v* sW4 = (f4v*)sW;

    // ---- Phase 1: coalesced nontemporal staging -------------------------
    f4v bb0, bb1;
    bb0      = ntload4(&Bg[v4base + tid]);
    sP4[tid] = ntload4(&Pg[v4base + tid]);
    sV4[tid] = ntload4(&Vg[v4base + tid]);
    if (tid < V4PB - BLOCK) {                      // tids 0..255 (waves 0-3)
        bb1              = ntload4(&Bg[v4base + BLOCK + tid]);
        sP4[BLOCK + tid] = ntload4(&Pg[v4base + BLOCK + tid]);
        sV4[BLOCK + tid] = ntload4(&Vg[v4base + BLOCK + tid]);
    } else {                                       // tids 256..511 (waves 4-7)
        const int i = tid - (V4PB - BLOCK);        // 0..255
        sW4[i] = ntload4(&Wg4[w4base + i]);
    }
    __syncthreads();

    // ---- Phase 2: compute 2 rays/thread (stride-512; LDS stride-3 word
    //      addressing -> <=2-way bank aliasing, free) ----------------------
    #pragma unroll
    for (int j = 0; j < 2; ++j) {
        const int r = tid + j*BLOCK;
        const float px = sP[3*r+0], py = sP[3*r+1], pz = sP[3*r+2];
        const float vx = sV[3*r+0], vy = sV[3*r+1], vz = sV[3*r+2];

        // oc = P - center, center=(0,0,60), R^2 = 2500
        const float ocx = px, ocy = py, ocz = pz - 60.0f;
        const float b = ocx*vx + ocy*vy + ocz*vz;
        const float c = ocx*ocx + ocy*ocy + ocz*ocz - 2500.0f;
        const float disc = b*b - c;
        const bool valid_collision = (disc >= 0.0f);
        const float sqrt_disc = valid_collision ? __builtin_amdgcn_sqrtf(disc) : 0.0f;
        const float tt = -b - sqrt_disc;

        const float Xx = px + tt*vx;
        const float Xy = py + tt*vy;
        const float Xz = pz + tt*vz;

        const float invR = 1.0f / 50.0f;
        const float nx = Xx * invR;
        const float ny = Xy * invR;
        const float nz = (Xz - 60.0f) * invR;

        const float dotVN = vx*nx + vy*ny + vz*nz;
        const float s = (dotVN > 0.0f) ? -1.0f : 1.0f;
        const float nfx = s*nx, nfy = s*ny, nfz = s*nz;

        const float cos_i = -(vx*nfx + vy*nfy + vz*nfz);

        const float l = sW[r];
        const float inv_l2 = __builtin_amdgcn_rcpf(l * l);
        const float n2 = 1.5046f + 0.0042f * inv_l2;   // n1 = 1.0
        const float eta = __builtin_amdgcn_rcpf(n2);

        const float sin2_t = eta*eta*(1.0f - cos_i*cos_i);
        const bool tir = (sin2_t > 1.0f);
        const float cos_t = tir ? 0.0f : __builtin_amdgcn_sqrtf(1.0f - sin2_t);

        const float k = eta*cos_i - cos_t;
        float ox, oy, oz;
        if (tir) {
            ox = vx + 2.0f*cos_i*nfx;
            oy = vy + 2.0f*cos_i*nfy;
            oz = vz + 2.0f*cos_i*nfz;
        } else {
            ox = eta*vx + k*nfx;
            oy = eta*vy + k*nfy;
            oz = eta*vz + k*nfz;
        }

        const bool both = valid_collision && !tir;

        sP[3*r+0] = both ? Xx : 0.0f;
        sP[3*r+1] = both ? Xy : 0.0f;
        sP[3*r+2] = both ? Xz : 0.0f;
        sV[3*r+0] = both ? ox : 0.0f;
        sV[3*r+1] = both ? oy : 0.0f;
        sV[3*r+2] = both ? oz : 0.0f;
        sW[r]  = both ? l : 0.0f;
        sBV[r] = both ? 1.0f : 0.0f;
        sVR[r] = tir ? 0.0f : 1.0f;
    }
    __syncthreads();

    // ---- Phase 3: fully coalesced nontemporal stores --------------------
    {
        const int i = tid;
        ntstore4(sP4[i], &outP[v4base + i]);
        ntstore4(sV4[i], &outV[v4base + i]);
        const int f = 4*i;
        f4v ob = bb0;
        ob.x *= sBV[(f+0)/3];
        ob.y *= sBV[(f+1)/3];
        ob.z *= sBV[(f+2)/3];
        ob.w *= sBV[(f+3)/3];
        ntstore4(ob, &outB[v4base + i]);
    }
    if (tid < V4PB - BLOCK) {                      // waves 0-3: second chunk
        const int i = BLOCK + tid;
        ntstore4(sP4[i], &outP[v4base + i]);
        ntstore4(sV4[i], &outV[v4base + i]);
        const int f = 4*i;
        f4v ob = bb1;
        ob.x *= sBV[(f+0)/3];
        ob.y *= sBV[(f+1)/3];
        ob.z *= sBV[(f+2)/3];
        ob.w *= sBV[(f+3)/3];
        ntstore4(ob, &outB[v4base + i]);
    } else {                                       // waves 4-7: scalar streams
        const int i = tid - (V4PB - BLOCK);        // 0..255
        ntstore4(sW4[i],           &outW [w4base + i]);
        ntstore4(((f4v*)sBV)[i],   &outBV[w4base + i]);
        ntstore4(((f4v*)sVR)[i],   &outVR[w4base + i]);
    }
}

extern "C" void kernel_launch(void* const* d_in, const int* in_sizes, int n_in,
                              void* d_out, int out_size, void* d_ws, size_t ws_size,
                              hipStream_t stream) {
    const int N = in_sizes[3];           // rays_wavelength element count
    const int nBlocks = N / RPB;

    const f4v* Pg  = (const f4v*)d_in[0];
    const f4v* Vg  = (const f4v*)d_in[1];
    const f4v* Bg  = (const f4v*)d_in[2];
    const f4v* Wg4 = (const f4v*)d_in[3];

    float* out = (float*)d_out;
    f4v* outP  = (f4v*)(out + (size_t)0  * N);
    f4v* outV  = (f4v*)(out + (size_t)3  * N);
    f4v* outB  = (f4v*)(out + (size_t)6  * N);
    f4v* outW  = (f4v*)(out + (size_t)9  * N);
    f4v* outBV = (f4v*)(out + (size_t)10 * N);
    f4v* outVR = (f4v*)(out + (size_t)11 * N);

    refract_lds_kernel<<<nBlocks, BLOCK, 0, stream>>>(Pg, Vg, Bg, Wg4,
                                                      outP, outV, outB, outW,
                                                      outBV, outVR);
}